// Round 8
// baseline (2858.816 us; speedup 1.0000x reference)
//
#include <hip/hip_runtime.h>
#include <math.h>

// ---------------------------------------------------------------------------
// GP posterior mean:
//   k_outer : separable NUFFT outer products, fp32 atomic-free partials
//             (full-tile acc[8][8], conflict-free LDS, (256,2) — best-known
//             config, 366 us; half-tile and (256,4) both regress).
//   k_reduce: partials -> fp32 circulant table vcf + fp64 rhs b.
//   k_cg_solve: ONE launch, ONE 1024-thread block. 50 CG iterations with the
//             Toeplitz apply as an in-LDS 128x128 radix-2 FFT conv
//             (DIF fwd / DIT inv, no bit-reversal needed since Vf is built by
//             the same forward path). r/p/x in registers (fp64), dots fp64.
//             Kills the 50-launch ~22us/iter structural overhead of R4-R7.
//   k_eval  : posterior mean at test points from al = ws*x_50.
// ---------------------------------------------------------------------------

typedef float f2 __attribute__((ext_vector_type(2)));
#define PB 16

__device__ inline f2 f2s(float s) { return (f2){s, s}; }
__device__ inline f2 cmulf(f2 a, f2 b) {   // a*b
    return (f2){a.x * b.x - a.y * b.y, a.x * b.y + a.y * b.x};
}
__device__ inline f2 cmulcf(f2 a, f2 b) {  // a*conj(b)
    return (f2){a.x * b.x + a.y * b.y, a.y * b.x - a.x * b.y};
}

// exp(i*pi*x*m) with fp64 angle reduction, scaled
__device__ inline f2 phasef(float xv, float m, float scale) {
    double ang = (double)xv * (double)m;
    double r = ang - 2.0 * rint(ang * 0.5);
    float sn, cs;
    sincospif((float)r, &sn, &cs);
    return (f2){cs * scale, sn * scale};
}

// ---------------------------------------------------------------------------
// k_outer: blocks [0,cv) accumulate a private fp32 partial of the raw
// 128x128 v-tile (slot 127 in each dim = zero pad); blocks [cv,cv+cf) a
// private 64x64 Fy partial (y folded into dim-1 phase). No atomics.
// v[a,b]  = sum_n exp(i pi x0 (a-63)) exp(i pi x1 (b-63)),  a,b in [0,126]
// Fy[a,b] = sum_n y_n exp(-i pi x0 (a-32)) exp(-i pi x1 (b-32))
// NOTE: (256,2). (256,4) caps VGPR at 64 -> spills acc (R6: 370->2464 us).
// NOTE: h2/out layout tx+16*j is conflict-free; tx*8+j gives 2.2e7 conflicts.
// ---------------------------------------------------------------------------
__global__ __launch_bounds__(256, 2) void k_outer(const float* __restrict__ x,
                                                  const float* __restrict__ y,
                                                  float* __restrict__ pv,
                                                  float* __restrict__ pf,
                                                  int N, int cv, int cf)
{
    __shared__ f2 hs[PB][256];
    __shared__ float xs0[PB], xs1[PB], ys[PB];

    int bx = blockIdx.x;
    int t  = threadIdx.x;
    int ty = t >> 4, tx = t & 15;

    if (bx < cv) {
        int CP = (N + cv - 1) / cv;
        int n0 = bx * CP, n1 = min(N, n0 + CP);

        f2 acc[8][8];
        #pragma unroll
        for (int i = 0; i < 8; ++i)
            #pragma unroll
            for (int j = 0; j < 8; ++j) acc[i][j] = (f2){0.f, 0.f};

        for (int s = n0; s < n1; s += PB) {
            int cnt = min(PB, n1 - s);
            __syncthreads();
            if (t < cnt) {
                xs0[t] = x[2 * (s + t)];
                xs1[t] = x[2 * (s + t) + 1];
            }
            __syncthreads();
            for (int p = 0; p < cnt; ++p) {
                f2 g;
                if (t < 128)
                    g = (t == 127) ? (f2){0.f, 0.f} : phasef(xs0[p], (float)t - 63.f, 1.f);
                else {
                    int c = t - 128;
                    g = (c == 127) ? (f2){0.f, 0.f} : phasef(xs1[p], (float)c - 63.f, 1.f);
                }
                hs[p][t] = g;
            }
            __syncthreads();
            for (int p = 0; p < cnt; ++p) {
                f2 h1[8], h2[8], h2s[8];
                #pragma unroll
                for (int i = 0; i < 8; ++i) h1[i] = hs[p][ty * 8 + i];
                #pragma unroll
                for (int j = 0; j < 8; ++j) {
                    f2 b = hs[p][128 + tx + 16 * j];
                    h2[j] = b;
                    h2s[j] = (f2){-b.y, b.x};
                }
                #pragma unroll
                for (int i = 0; i < 8; ++i)
                    #pragma unroll
                    for (int j = 0; j < 8; ++j) {
                        acc[i][j] = acc[i][j] + f2s(h1[i].x) * h2[j];
                        acc[i][j] = acc[i][j] + f2s(h1[i].y) * h2s[j];
                    }
            }
        }
        __syncthreads();
        f2* out = (f2*)pv + (size_t)bx * 16384;
        #pragma unroll
        for (int i = 0; i < 8; ++i) {
            int a = ty * 8 + i;
            #pragma unroll
            for (int j = 0; j < 8; ++j)
                out[a * 128 + tx + 16 * j] = acc[i][j];
        }
    } else {
        int chunk = bx - cv;
        int CP = (N + cf - 1) / cf;
        int n0 = chunk * CP, n1 = min(N, n0 + CP);

        f2 acc[4][4];
        #pragma unroll
        for (int i = 0; i < 4; ++i)
            #pragma unroll
            for (int j = 0; j < 4; ++j) acc[i][j] = (f2){0.f, 0.f};

        for (int s = n0; s < n1; s += PB) {
            int cnt = min(PB, n1 - s);
            __syncthreads();
            if (t < cnt) {
                xs0[t] = x[2 * (s + t)];
                xs1[t] = x[2 * (s + t) + 1];
                ys[t]  = y[s + t];
            }
            __syncthreads();
            for (int p2 = 0; p2 < cnt; p2 += 2) {
                int p = p2 + (t >> 7);
                int c = t & 127;
                if (p < cnt) {
                    f2 g;
                    if (c < 64) g = phasef(xs0[p], (float)(32 - c), ys[p]);
                    else        g = phasef(xs1[p], (float)(32 - (c - 64)), 1.f);
                    hs[p][c] = g;
                }
            }
            __syncthreads();
            for (int p = 0; p < cnt; ++p) {
                f2 h1[4], h2[4], h2s[4];
                #pragma unroll
                for (int i = 0; i < 4; ++i) h1[i] = hs[p][ty * 4 + i];
                #pragma unroll
                for (int j = 0; j < 4; ++j) {
                    f2 b = hs[p][64 + tx + 16 * j];
                    h2[j] = b;
                    h2s[j] = (f2){-b.y, b.x};
                }
                #pragma unroll
                for (int i = 0; i < 4; ++i)
                    #pragma unroll
                    for (int j = 0; j < 4; ++j) {
                        acc[i][j] = acc[i][j] + f2s(h1[i].x) * h2[j];
                        acc[i][j] = acc[i][j] + f2s(h1[i].y) * h2s[j];
                    }
            }
        }
        __syncthreads();
        f2* out = (f2*)pf + (size_t)chunk * 4096;
        #pragma unroll
        for (int i = 0; i < 4; ++i) {
            int a = ty * 4 + i;
            #pragma unroll
            for (int j = 0; j < 4; ++j)
                out[a * 64 + tx + 16 * j] = acc[i][j];
        }
    }
}

// ---------------------------------------------------------------------------
// k_reduce: v partials sliced 8-way per element -> fp32 atomicAdd into the
// CIRCULANT table vcf[q1*128+q2] (raw index a=(q+63)&127; a==127 hits the
// zero pad -> vc[q=64]=0 automatically). Fy partials serial per element
// (fp64) -> rvec = b = ws*Fy. Thread space: [0,131072) v, [131072,135168) Fy.
// ---------------------------------------------------------------------------
__global__ __launch_bounds__(256) void k_reduce(const float* __restrict__ pv,
                                                const float* __restrict__ pf,
                                                const float* __restrict__ wsv,
                                                float* __restrict__ vcf,
                                                double2* __restrict__ rvec,
                                                int cv, int cf)
{
    int id = blockIdx.x * 256 + threadIdx.x;
    if (id < 131072) {
        int e = id >> 3, sl = id & 7;
        int q1 = e >> 7, q2 = e & 127;
        int a = (q1 + 63) & 127, b = (q2 + 63) & 127;
        int cn = cv >> 3;
        const float* src = pv + (size_t)(a * 128 + b) * 2
                              + (size_t)(sl * cn) * 32768;
        float sx = 0.f, sy = 0.f;
        for (int c = 0; c < cn; ++c) { sx += src[0]; sy += src[1]; src += 32768; }
        atomicAdd(&vcf[e * 2], sx);
        atomicAdd(&vcf[e * 2 + 1], sy);
    } else {
        int e = id - 131072;          // 0..4095
        const float* s2p = pf + (size_t)e * 2;
        double fx = 0.0, fy2 = 0.0;
        for (int c = 0; c < cf; ++c) { fx += (double)s2p[0]; fy2 += (double)s2p[1]; s2p += 8192; }
        double w = (double)wsv[e];
        rvec[e] = make_double2(w * fx, w * fy2);
    }
}

// ---------------------------------------------------------------------------
// k_cg_solve: ONE block, 1024 threads (16 waves). LDS: Z[128][129] f2
// (129-stride -> exactly 4 words/bank on row AND col passes, conflict-free).
// Setup: Vf = 2D DIF-forward of vcf (scrambled order). Per iteration:
// z=ws*p (fp32) -> fwd rows(64)/cols(128) DIF -> *Vf -> inv cols/rows DIT
// -> Tz/16384 -> Ap; fp64 dots (pAp, then true <r,r>); fp64 r/p/x updates in
// registers. alpha = rz/(pAp+1e-30), beta = rz_new/(rz+1e-30) == reference.
// Output: alg = ws*x_50 (fp32 complex).
// ---------------------------------------------------------------------------
__device__ inline double blk_reduce(double v, double* red, double* sc,
                                    int wid, int m, int tid)
{
    #pragma unroll
    for (int off = 32; off > 0; off >>= 1) v += __shfl_down(v, off);
    if (m == 0) red[wid] = v;
    __syncthreads();
    if (tid == 0) {
        double s = 0.0;
        #pragma unroll
        for (int i = 0; i < 16; ++i) s += red[i];
        sc[0] = s;
    }
    __syncthreads();
    double out = sc[0];
    __syncthreads();
    return out;
}

__global__ __launch_bounds__(1024) void k_cg_solve(
        const float* __restrict__ vcf, float* __restrict__ Vf,
        const double2* __restrict__ rvec, const float* __restrict__ wsv,
        const float* __restrict__ sig2, float* __restrict__ alg)
{
    __shared__ f2 Z[128 * 129];
    __shared__ f2 tw[64];
    __shared__ double red[16];
    __shared__ double sc[1];

    int tid = threadIdx.x;
    int wid = tid >> 6, m = tid & 63;

    if (tid < 64) {
        float sn, cs;
        sincospif(-(float)tid / 64.f, &sn, &cs);
        tw[tid] = (f2){cs, sn};
    }
    __syncthreads();

    // ---- Vf setup: load vc, 2D forward DIF, store (scrambled order is fine)
    for (int i = tid; i < 16384; i += 1024)
        Z[(i >> 7) * 129 + (i & 127)] = ((const f2*)vcf)[i];
    __syncthreads();
    for (int k = 7; k >= 1; --k) {               // rows (all 128)
        int h = 1 << (k - 1), L = h << 1;
        int g = m >> (k - 1), j = m & (h - 1);
        f2 w = tw[j << (7 - k)];
        for (int rr = wid; rr < 128; rr += 16) {
            f2* row = Z + rr * 129;
            int i0 = g * L + j;
            f2 u = row[i0], v = row[i0 + h];
            f2 d = u - v;
            row[i0] = u + v;
            row[i0 + h] = cmulf(d, w);
        }
        __syncthreads();
    }
    for (int k = 7; k >= 1; --k) {               // cols
        int h = 1 << (k - 1), L = h << 1;
        int g = m >> (k - 1), j = m & (h - 1);
        f2 w = tw[j << (7 - k)];
        int i0 = (g * L + j) * 129;
        int i1 = i0 + h * 129;
        for (int cc = wid; cc < 128; cc += 16) {
            f2 u = Z[i0 + cc], v = Z[i1 + cc];
            f2 d = u - v;
            Z[i0 + cc] = u + v;
            Z[i1 + cc] = cmulf(d, w);
        }
        __syncthreads();
    }
    for (int i = tid; i < 16384; i += 1024)
        ((f2*)Vf)[i] = Z[(i >> 7) * 129 + (i & 127)];
    __syncthreads();

    // ---- CG state in registers
    double2 pR[4], rR[4], xR[4];
    float wsr[4];
    int zix[4];
    double rzp = 0.0;
    #pragma unroll
    for (int s = 0; s < 4; ++s) {
        int e = tid + (s << 10);
        double2 bv = rvec[e];
        pR[s] = bv; rR[s] = bv; xR[s] = make_double2(0.0, 0.0);
        wsr[s] = wsv[e];
        zix[s] = (e >> 6) * 129 + (e & 63);
        rzp += bv.x * bv.x + bv.y * bv.y;
    }
    double rz = blk_reduce(rzp, red, sc, wid, m, tid);
    double s2 = (double)sig2[0];
    const double inv16384 = 1.0 / 16384.0;

    for (int it = 0; it < 50; ++it) {
        // z = ws*p into zeroed Z
        for (int i = tid; i < 16512; i += 1024) Z[i] = (f2){0.f, 0.f};
        __syncthreads();
        #pragma unroll
        for (int s = 0; s < 4; ++s)
            Z[zix[s]] = (f2){(float)((double)wsr[s] * pR[s].x),
                             (float)((double)wsr[s] * pR[s].y)};
        __syncthreads();

        // forward rows 0..63 (rows 64..127 are zero)
        for (int k = 7; k >= 1; --k) {
            int h = 1 << (k - 1), L = h << 1;
            int g = m >> (k - 1), j = m & (h - 1);
            f2 w = tw[j << (7 - k)];
            for (int rr = wid; rr < 64; rr += 16) {
                f2* row = Z + rr * 129;
                int i0 = g * L + j;
                f2 u = row[i0], v = row[i0 + h];
                f2 d = u - v;
                row[i0] = u + v;
                row[i0 + h] = cmulf(d, w);
            }
            __syncthreads();
        }
        // forward cols (all 128)
        for (int k = 7; k >= 1; --k) {
            int h = 1 << (k - 1), L = h << 1;
            int g = m >> (k - 1), j = m & (h - 1);
            f2 w = tw[j << (7 - k)];
            int i0 = (g * L + j) * 129;
            int i1 = i0 + h * 129;
            for (int cc = wid; cc < 128; cc += 16) {
                f2 u = Z[i0 + cc], v = Z[i1 + cc];
                f2 d = u - v;
                Z[i0 + cc] = u + v;
                Z[i1 + cc] = cmulf(d, w);
            }
            __syncthreads();
        }
        // pointwise *= Vf (matching scrambled order)
        for (int q = 0; q < 16; ++q) {
            int i = tid + (q << 10);
            int zi = (i >> 7) * 129 + (i & 127);
            Z[zi] = cmulf(Z[zi], ((const f2*)Vf)[i]);
        }
        __syncthreads();
        // inverse cols (DIT, scrambled->natural)
        for (int k = 1; k <= 7; ++k) {
            int h = 1 << (k - 1), L = h << 1;
            int g = m >> (k - 1), j = m & (h - 1);
            f2 w = tw[j << (7 - k)];
            int i0 = (g * L + j) * 129;
            int i1 = i0 + h * 129;
            for (int cc = wid; cc < 128; cc += 16) {
                f2 u = Z[i0 + cc];
                f2 vw = cmulcf(Z[i1 + cc], w);
                Z[i0 + cc] = u + vw;
                Z[i1 + cc] = u - vw;
            }
            __syncthreads();
        }
        // inverse rows 0..63 (only those needed)
        for (int k = 1; k <= 7; ++k) {
            int h = 1 << (k - 1), L = h << 1;
            int g = m >> (k - 1), j = m & (h - 1);
            f2 w = tw[j << (7 - k)];
            for (int rr = wid; rr < 64; rr += 16) {
                f2* row = Z + rr * 129;
                int i0 = g * L + j;
                f2 u = row[i0];
                f2 vw = cmulcf(row[i0 + h], w);
                row[i0] = u + vw;
                row[i0 + h] = u - vw;
            }
            __syncthreads();
        }

        // Ap, <p,Ap>
        double papp = 0.0;
        #pragma unroll
        for (int s = 0; s < 4; ++s) {
            f2 tz = Z[zix[s]];
            double apx = (double)wsr[s] * (double)tz.x * inv16384 + s2 * pR[s].x;
            double apy = (double)wsr[s] * (double)tz.y * inv16384 + s2 * pR[s].y;
            papp += pR[s].x * apx + pR[s].y * apy;
        }
        double pap = blk_reduce(papp, red, sc, wid, m, tid);
        double alpha = rz / (pap + 1e-30);

        double rrp = 0.0;
        #pragma unroll
        for (int s = 0; s < 4; ++s) {
            f2 tz = Z[zix[s]];
            double apx = (double)wsr[s] * (double)tz.x * inv16384 + s2 * pR[s].x;
            double apy = (double)wsr[s] * (double)tz.y * inv16384 + s2 * pR[s].y;
            xR[s].x += alpha * pR[s].x; xR[s].y += alpha * pR[s].y;
            rR[s].x -= alpha * apx;     rR[s].y -= alpha * apy;
            rrp += rR[s].x * rR[s].x + rR[s].y * rR[s].y;
        }
        double rzn = blk_reduce(rrp, red, sc, wid, m, tid);
        double beta = rzn / (rz + 1e-30);
        rz = rzn;
        #pragma unroll
        for (int s = 0; s < 4; ++s) {
            pR[s].x = rR[s].x + beta * pR[s].x;
            pR[s].y = rR[s].y + beta * pR[s].y;
        }
    }

    // al = ws * x_50
    #pragma unroll
    for (int s = 0; s < 4; ++s) {
        int e = tid + (s << 10);
        ((f2*)alg)[e] = (f2){(float)((double)wsr[s] * xR[s].x),
                             (float)((double)wsr[s] * xR[s].y)};
    }
}

// ---------------------------------------------------------------------------
// k_eval: mu[b] = Re( sum_j e1[j] * sum_k al[j,k] e2[k] ), al = ws*x_50.
// ---------------------------------------------------------------------------
__global__ __launch_bounds__(64) void k_eval(const float* __restrict__ xnew,
                                             const float* __restrict__ alg,
                                             float* __restrict__ out, int B)
{
    __shared__ float2 al[4096];
    int t = threadIdx.x;
    int b = blockIdx.x * 64 + t;
    for (int i = t; i < 4096; i += 64) {
        f2 v = ((const f2*)alg)[i];
        al[i] = make_float2(v.x, v.y);
    }
    float x0 = 0.f, x1 = 0.f;
    if (b < B) { x0 = xnew[2 * b]; x1 = xnew[2 * b + 1]; }
    __syncthreads();
    double2 wstep; { double sn, cs; sincospi((double)x1, &sn, &cs); wstep = make_double2(cs, sn); }
    double mu = 0.0;
    for (int jg = 0; jg < 4; ++jg) {
        float2 tacc[16];
        for (int q = 0; q < 16; ++q) tacc[q] = make_float2(0.f, 0.f);
        double2 e2; { double sn, cs; sincospi(-32.0 * (double)x1, &sn, &cs); e2 = make_double2(cs, sn); }
        for (int k = 0; k < 64; ++k) {
            float2 e2f = make_float2((float)e2.x, (float)e2.y);
            for (int q = 0; q < 16; ++q) {
                int j = jg * 16 + q;
                float2 a = al[j * 64 + k];
                tacc[q].x += a.x * e2f.x - a.y * e2f.y;
                tacc[q].y += a.x * e2f.y + a.y * e2f.x;
            }
            e2 = make_double2(e2.x * wstep.x - e2.y * wstep.y,
                              e2.x * wstep.y + e2.y * wstep.x);
        }
        for (int q = 0; q < 16; ++q) {
            int j = jg * 16 + q;
            double sn, cs;
            sincospi((double)x0 * (double)(j - 32), &sn, &cs);
            mu += cs * (double)tacc[q].x - sn * (double)tacc[q].y;
        }
    }
    if (b < B) out[b] = (float)mu;
}

// ---------------------------------------------------------------------------

extern "C" void kernel_launch(void* const* d_in, const int* in_sizes, int n_in,
                              void* d_out, int out_size, void* d_ws, size_t ws_size,
                              hipStream_t stream)
{
    const float* x    = (const float*)d_in[0];
    const float* y    = (const float*)d_in[1];
    const float* xnew = (const float*)d_in[2];
    const float* wsv  = (const float*)d_in[3];
    const float* sig2 = (const float*)d_in[4];
    int N = in_sizes[1];
    int B = in_sizes[2] / 2;

    char* base = (char*)d_ws;
    size_t o = 0;
    float*   vcf  = (float*)(base + o);   o += 131072;   // 128x128 circulant vc (fp32)
    float*   Vf   = (float*)(base + o);   o += 131072;   // scrambled 2D FFT of vc
    double2* rvec = (double2*)(base + o); o += 65536;    // b = ws*Fy (fp64)
    float*   alg  = (float*)(base + o);   o += 32768;    // ws*x_50 (fp32 complex)
    size_t avail = (ws_size > o) ? ws_size - o : 0;
    int cv = (int)(avail / 139264);                      // 128KB v + 8KB fy per unit
    if (cv > 384) cv = 384;
    if (cv < 16) cv = 16;
    cv &= ~15;                                           // cv%8==0, cf%4==0
    int cf = cv / 4;
    float* pv = (float*)(base + o); o += (size_t)cv * 131072;
    float* pf = (float*)(base + o);

    hipMemsetAsync(vcf, 0, 131072, stream);              // fp32 atomic target

    k_outer<<<cv + cf, 256, 0, stream>>>(x, y, pv, pf, N, cv, cf);
    k_reduce<<<528, 256, 0, stream>>>(pv, pf, wsv, vcf, rvec, cv, cf);
    k_cg_solve<<<1, 1024, 0, stream>>>(vcf, Vf, rvec, wsv, sig2, alg);
    k_eval<<<(B + 63) / 64, 64, 0, stream>>>(xnew, alg, (float*)d_out, B);
}